// Round 2
// baseline (574.891 us; speedup 1.0000x reference)
//
#include <hip/hip_runtime.h>

#define B_ 32
#define D_ 128
#define T_ 1024
#define K_ 4096
#define NROWS (B_ * T_)   // 32768
#define BM 64             // rows per workgroup
#define BN 64             // codes per tile
#define LP 132            // padded LDS row stride (floats)

struct MI { float m; int i; };

// Block mul->add contraction so the square is rounded separately (numpy computes
// t = a*a as an elementwise array op, THEN sums — no fma in the sum).
__device__ __forceinline__ float opaquef(float x) { asm volatile("" : "+v"(x)); return x; }

// numpy pairwise_sum base case for n=128 (n <= PW_BLOCKSIZE): 8 scalar
// accumulators, then ((r0+r1)+(r2+r3))+((r4+r5)+(r6+r7)). Bit-exact replica.
__device__ float np_sumsq128(const float* a) {
  float r[8];
#pragma unroll
  for (int j = 0; j < 8; ++j) r[j] = opaquef(a[j] * a[j]);
#pragma unroll
  for (int i = 8; i < 128; i += 8) {
#pragma unroll
    for (int j = 0; j < 8; ++j) r[j] = r[j] + opaquef(a[i + j] * a[i + j]);
  }
  return ((r[0] + r[1]) + (r[2] + r[3])) + ((r[4] + r[5]) + (r[6] + r[7]));
}

__global__ void wsq_kernel(const float* __restrict__ W, float* __restrict__ wsq) {
  int k = blockIdx.x * blockDim.x + threadIdx.x;
  if (k < K_) wsq[k] = np_sumsq128(W + (size_t)k * D_);
}

__global__ __launch_bounds__(256, 2) void argmin_kernel(
    const float* __restrict__ x, const float* __restrict__ W,
    const float* __restrict__ wsq, int* __restrict__ qout,
    float* __restrict__ out2) {
  __shared__ float xs[BM][LP];
  __shared__ float wsm[BN][LP];
  __shared__ float xsqs[BM];
  const int tid = threadIdx.x;
  const int blk = blockIdx.x;
  const int b  = blk / (T_ / BM);
  const int t0 = (blk % (T_ / BM)) * BM;
  const int tx = tid & 15;   // code group
  const int ty = tid >> 4;   // row group (0..15)

  // stage x tile: xs[tt][d] = x[b, d, t0+tt]   (coalesced along t)
  {
    int tt = tid & 63;
    int d0 = (tid >> 6) * 32;
    for (int dd = 0; dd < 32; ++dd) {
      int d = d0 + dd;
      xs[tt][d] = x[((size_t)b * D_ + d) * T_ + t0 + tt];
    }
  }
  __syncthreads();
  // per-row ||x||^2 with numpy's exact summation order
  if (tid < BM) xsqs[tid] = np_sumsq128(&xs[tid][0]);
  __syncthreads();

  float xq[4];
#pragma unroll
  for (int i = 0; i < 4; ++i) xq[i] = xsqs[ty + 16 * i];

  float m1[4];
  int   i1[4];
#pragma unroll
  for (int i = 0; i < 4; ++i) { m1[i] = 3.4e38f; i1[i] = 0x7fffffff; }

  for (int kt = 0; kt < K_ / BN; ++kt) {
    const int c0 = kt * BN;
    __syncthreads();  // prev compute done
    for (int i4 = tid; i4 < BN * D_ / 4; i4 += 256) {
      int row = i4 >> 5;
      int dc  = (i4 & 31) << 2;
      *(float4*)&wsm[row][dc] = *(const float4*)&W[(size_t)(c0 + row) * D_ + dc];
    }
    __syncthreads();

    float acc[4][4];
#pragma unroll
    for (int i = 0; i < 4; ++i)
#pragma unroll
      for (int j = 0; j < 4; ++j) acc[i][j] = 0.f;

    // mm[n,k]: single-accumulator fma chain, ascending d (OpenBLAS sgemm order)
    for (int d = 0; d < D_; d += 4) {
      float4 av[4], bv[4];
#pragma unroll
      for (int i = 0; i < 4; ++i) av[i] = *(const float4*)&xs[ty + 16 * i][d];
#pragma unroll
      for (int j = 0; j < 4; ++j) bv[j] = *(const float4*)&wsm[tx + 16 * j][d];
#pragma unroll
      for (int i = 0; i < 4; ++i)
#pragma unroll
        for (int j = 0; j < 4; ++j) {
          acc[i][j] = __fmaf_rn(av[i].x, bv[j].x, acc[i][j]);
          acc[i][j] = __fmaf_rn(av[i].y, bv[j].y, acc[i][j]);
          acc[i][j] = __fmaf_rn(av[i].z, bv[j].z, acc[i][j]);
          acc[i][j] = __fmaf_rn(av[i].w, bv[j].w, acc[i][j]);
        }
    }

#pragma unroll
    for (int j = 0; j < 4; ++j) {
      int k = c0 + tx + 16 * j;   // ascending k within thread across j, kt
      float wq = wsq[k];
#pragma unroll
      for (int i = 0; i < 4; ++i) {
        // t = RN(wq - 2*mm)  (2*mm is exact; fmaf gives the identical single rounding)
        float t = __fmaf_rn(-2.0f, acc[i][j], wq);
        // dist = RN(t + xsq)  — the quantizing add; MUST happen before compare
        float v = __fadd_rn(t, xq[i]);
        if (v < m1[i]) { m1[i] = v; i1[i] = k; }   // strict < => first occurrence
      }
    }
  }

  __syncthreads();
  MI* red = (MI*)&wsm[0][0];   // reuse W-tile LDS (8 KB needed)
#pragma unroll
  for (int i = 0; i < 4; ++i) {
    MI t; t.m = m1[i]; t.i = i1[i];
    red[(ty + 16 * i) * 16 + tx] = t;
  }
  __syncthreads();

  if (tid < BM) {
    float M = 3.4e38f;
    int   I = 0x7fffffff;
    for (int j = 0; j < 16; ++j) {
      MI t = red[tid * 16 + j];
      if (t.m < M || (t.m == M && t.i < I)) { M = t.m; I = t.i; }
    }
    int rg = b * T_ + t0 + tid;
    qout[rg] = I;
    out2[rg] = (float)I;
  }
}

// out0[r, d] = W[q[r], d]  — coalesced along d
__global__ void scatter0_kernel(const float* __restrict__ W,
                                const int* __restrict__ q,
                                float* __restrict__ out0) {
  int r = blockIdx.x * 2 + (threadIdx.x >> 7);
  int d = threadIdx.x & 127;
  out0[(size_t)r * D_ + d] = W[(size_t)q[r] * D_ + d];
}

// out1[b, d, t] = W[q[b,t], d]  — coalesced along t
__global__ void scatter1_kernel(const float* __restrict__ W,
                                const int* __restrict__ q,
                                float* __restrict__ out1) {
  int b = blockIdx.x >> 7;
  int d = blockIdx.x & 127;
  for (int t = threadIdx.x; t < T_; t += 256) {
    int k = q[b * T_ + t];
    out1[((size_t)b * D_ + d) * T_ + t] = W[(size_t)k * D_ + d];
  }
}

extern "C" void kernel_launch(void* const* d_in, const int* in_sizes, int n_in,
                              void* d_out, int out_size, void* d_ws, size_t ws_size,
                              hipStream_t stream) {
  const float* x = (const float*)d_in[0];
  const float* W = (const float*)d_in[1];
  float* out  = (float*)d_out;
  float* out0 = out;                           // [B,T,D]  4194304
  float* out1 = out + (size_t)NROWS * D_;      // [B,D,T]  4194304
  float* out2 = out + 2 * (size_t)NROWS * D_;  // [B,T]    32768 (as float)

  float* wsq = (float*)d_ws;                              // 16 KB
  int*   q   = (int*)((char*)d_ws + K_ * sizeof(float));  // 128 KB

  wsq_kernel<<<K_ / 256, 256, 0, stream>>>(W, wsq);
  argmin_kernel<<<NROWS / BM, 256, 0, stream>>>(x, W, wsq, q, out2);
  scatter0_kernel<<<NROWS / 2, 256, 0, stream>>>(W, q, out0);
  scatter1_kernel<<<B_ * D_, 256, 0, stream>>>(W, q, out1);
}